// Round 5
// baseline (185.672 us; speedup 1.0000x reference)
//
#include <hip/hip_runtime.h>

// ---------- types ----------
typedef short short8 __attribute__((ext_vector_type(8)));        // 8 bf16 MFMA A/B frag
typedef float floatx4 __attribute__((ext_vector_type(4)));       // MFMA C/D frag
typedef unsigned short ushortx4 __attribute__((ext_vector_type(4)));

__device__ __forceinline__ unsigned short f2bf(float f) {
    unsigned u = __float_as_uint(f);
    u += 0x7fffu + ((u >> 16) & 1u);   // RNE
    return (unsigned short)(u >> 16);
}
__device__ __forceinline__ unsigned packbf(float a, float b) {
    return (unsigned)f2bf(a) | ((unsigned)f2bf(b) << 16);
}

#define MFMA16(a, b, c)  __builtin_amdgcn_mfma_f32_16x16x32_bf16((a), (b), (c), 0, 0, 0)

// ---------- ws layout (bytes) ----------
static constexpr size_t XB_OFF   = 0;                    // x bf16 [8192][1024]  16 MB
static constexpr size_t Q_OFF    = 16u << 20;            // q*QSCALE bf16 [8192][128] 2 MB
static constexpr size_t K_OFF    = 18u << 20;            // k bf16 [8192][128]        2 MB
static constexpr size_t VT_OFF   = 20u << 20;            // v^T bf16 [128][8192]      2 MB
static constexpr size_t WFCT_OFF = 22u << 20;            // W_fc^T bf16 [128][1024] 256 KB
static constexpr size_t WGT_OFF  = WFCT_OFF + 262144;
static constexpr size_t WQT_OFF  = WGT_OFF + 262144;     // W_q^T bf16 [128][128] 32 KB
static constexpr size_t WKT_OFF  = WQT_OFF + 32768;
static constexpr size_t WVT_OFF  = WKT_OFF + 32768;
static constexpr size_t LP_OFF   = 23u << 20;            // l partials fp32 [nsplit][8192] (max 8: 256 KB)
static constexpr size_t OS_OFF   = LP_OFF + 262144;      // o-scalar partials fp32 [nsplit][8192]

// log2(e)/sqrt(128): folded into stored q so P = exp2(S)
static constexpr float QSCALE = 0.1275174308f;

// ---------- K0: x fp32 -> bf16 streaming convert ----------
__global__ __launch_bounds__(256) void k_xcvt(const float* __restrict__ x,
                                              unsigned short* __restrict__ xb) {
    int i = (blockIdx.x * 256 + threadIdx.x) * 8;
    float4 a = *(const float4*)(x + i);
    float4 b = *(const float4*)(x + i + 4);
    short8 t;
    unsigned short* tp = (unsigned short*)&t;
    tp[0] = f2bf(a.x); tp[1] = f2bf(a.y); tp[2] = f2bf(a.z); tp[3] = f2bf(a.w);
    tp[4] = f2bf(b.x); tp[5] = f2bf(b.y); tp[6] = f2bf(b.z); tp[7] = f2bf(b.w);
    *(short8*)(xb + i) = t;
}

// ---------- K1: all weight transposes + fp32->bf16, one launch ----------
__global__ void k_transw_all(const float* __restrict__ wfc, const float* __restrict__ wg,
                             const float* __restrict__ wq, const float* __restrict__ wk,
                             const float* __restrict__ wv,
                             unsigned short* __restrict__ dfc, unsigned short* __restrict__ dg,
                             unsigned short* __restrict__ dq, unsigned short* __restrict__ dk,
                             unsigned short* __restrict__ dv) {
    int i = blockIdx.x * 256 + threadIdx.x;
    const float* s; unsigned short* d; int K, base;
    if (i < 131072)      { s = wfc; d = dfc; K = 1024; base = 0; }
    else if (i < 262144) { s = wg;  d = dg;  K = 1024; base = 131072; }
    else if (i < 278528) { s = wq;  d = dq;  K = 128;  base = 262144; }
    else if (i < 294912) { s = wk;  d = dk;  K = 128;  base = 278528; }
    else if (i < 311296) { s = wv;  d = dv;  K = 128;  base = 294912; }
    else return;
    int j = i - base;
    int kk = j >> 7, nn = j & 127;
    d[nn * K + kk] = f2bf(s[j]);
}

// ---------- K2: fused gated-linear + QKV (bf16 outputs) ----------
// grid 256 x 512 thr; block = 32 rows. Phase A has NO LDS staging and NO barriers:
// A-frags are direct global loads from pre-converted bf16 x (exact MFMA layout),
// B-frags from L2-resident transposed weights. 8 waves: w<4 -> fc cols (w&3)*32, w>=4 -> gate.
// Phase B: wave w -> cols w*48 of [q|k|v]; q pre-scaled by QSCALE; v stored transposed.
__global__ __launch_bounds__(512) void k_gq(const unsigned short* __restrict__ xb,
                                            const unsigned short* __restrict__ wfct,
                                            const unsigned short* __restrict__ wgt,
                                            const float* __restrict__ bfc,
                                            const float* __restrict__ bg,
                                            const unsigned short* __restrict__ wqt,
                                            const unsigned short* __restrict__ wkt,
                                            const unsigned short* __restrict__ wvt,
                                            const float* __restrict__ bq,
                                            const float* __restrict__ bk,
                                            const float* __restrict__ bv,
                                            unsigned short* __restrict__ q,
                                            unsigned short* __restrict__ kt,
                                            unsigned short* __restrict__ vt) {
    __shared__ __align__(16) float gbuf[32 * 132];
    __shared__ __align__(16) unsigned short hs[32 * 136];
    const int tid = threadIdx.x;
    const int i0 = blockIdx.x * 32;
    const int w = tid >> 6, lane = tid & 63;
    const int lr = lane & 15, lk = lane >> 4;

    const int isg = (w >= 4);
    const int ncol0 = (w & 3) * 32;
    const unsigned short* wt = isg ? wgt : wfct;

    floatx4 acc[2][2];
#pragma unroll
    for (int mt = 0; mt < 2; ++mt)
#pragma unroll
        for (int nt = 0; nt < 2; ++nt) acc[mt][nt] = (floatx4)0.0f;

    const unsigned short* xrow0 = xb + (size_t)(i0 + lr) * 1024 + lk * 8;
#pragma unroll 2
    for (int kc = 0; kc < 8; ++kc) {
#pragma unroll
        for (int ks = 0; ks < 4; ++ks) {
            short8 a[2], b[2];
#pragma unroll
            for (int mt = 0; mt < 2; ++mt)
                a[mt] = *(const short8*)(xrow0 + (size_t)mt * 16384 + kc * 128 + ks * 32);
#pragma unroll
            for (int nt = 0; nt < 2; ++nt)
                b[nt] = *(const short8*)(wt + (size_t)(ncol0 + nt * 16 + lr) * 1024 + kc * 128 + ks * 32 + lk * 8);
#pragma unroll
            for (int mt = 0; mt < 2; ++mt)
#pragma unroll
                for (int nt = 0; nt < 2; ++nt)
                    acc[mt][nt] = MFMA16(a[mt], b[nt], acc[mt][nt]);
        }
    }
    // epilogue A
    if (isg) {
#pragma unroll
        for (int mt = 0; mt < 2; ++mt)
#pragma unroll
            for (int nt = 0; nt < 2; ++nt) {
                int col = ncol0 + nt * 16 + lr;
                float bb = bg[col];
#pragma unroll
                for (int r = 0; r < 4; ++r) {
                    float v = acc[mt][nt][r] + bb;
                    gbuf[(mt * 16 + lk * 4 + r) * 132 + col] =
                        __builtin_amdgcn_rcpf(1.0f + __builtin_amdgcn_exp2f(-1.4426950408889634f * v));
                }
            }
    }
    __syncthreads();
    if (!isg) {
#pragma unroll
        for (int mt = 0; mt < 2; ++mt)
#pragma unroll
            for (int nt = 0; nt < 2; ++nt) {
                int col = ncol0 + nt * 16 + lr;
                float bb = bfc[col];
#pragma unroll
                for (int r = 0; r < 4; ++r) {
                    int row = mt * 16 + lk * 4 + r;
                    hs[row * 136 + col] = f2bf((acc[mt][nt][r] + bb) * gbuf[row * 132 + col]);
                }
            }
    }
    __syncthreads();

    // Phase B: q,k,v
    const unsigned short* wts[3] = {wqt, wkt, wvt};
    floatx4 qacc[2][3];
#pragma unroll
    for (int mt = 0; mt < 2; ++mt)
#pragma unroll
        for (int nt = 0; nt < 3; ++nt) qacc[mt][nt] = (floatx4)0.0f;

#pragma unroll
    for (int ks = 0; ks < 4; ++ks) {
        short8 a[2];
#pragma unroll
        for (int mt = 0; mt < 2; ++mt)
            a[mt] = *(const short8*)(hs + (mt * 16 + lr) * 136 + ks * 32 + lk * 8);
#pragma unroll
        for (int nt = 0; nt < 3; ++nt) {
            int c = w * 48 + nt * 16;
            int tt = c >> 7, cc = c & 127;
            short8 b = *(const short8*)(wts[tt] + (size_t)(cc + lr) * 128 + ks * 32 + lk * 8);
#pragma unroll
            for (int mt = 0; mt < 2; ++mt)
                qacc[mt][nt] = MFMA16(a[mt], b, qacc[mt][nt]);
        }
    }
    const float* bss[3] = {bq, bk, bv};
#pragma unroll
    for (int nt = 0; nt < 3; ++nt) {
        int c = w * 48 + nt * 16;
        int tt = c >> 7, cc = c & 127;
        int col = cc + lr;
        float bb = bss[tt][col];
        if (tt == 2) {
            // v: bf16 transposed, pack 4 consecutive rows (j) into one 8B store
#pragma unroll
            for (int mt = 0; mt < 2; ++mt) {
                ushortx4 pv;
#pragma unroll
                for (int r = 0; r < 4; ++r) pv[r] = f2bf(qacc[mt][nt][r] + bb);
                *(ushortx4*)(vt + (size_t)col * 8192 + i0 + mt * 16 + lk * 4) = pv;
            }
        } else {
            float sc = (tt == 0) ? QSCALE : 1.0f;
            unsigned short* dst = (tt == 0) ? q : kt;
#pragma unroll
            for (int mt = 0; mt < 2; ++mt)
#pragma unroll
                for (int r = 0; r < 4; ++r)
                    dst[(size_t)(i0 + mt * 16 + lk * 4 + r) * 128 + col] = f2bf((qacc[mt][nt][r] + bb) * sc);
        }
    }
}

// ---------- K3: flash attention v5 (bf16, W_out folded into epilogue) ----------
// grid (64, nsplit) x 256 thr; block = 128 Q rows, 4 waves, wave w owns q-rows w*32..+32.
// Per 64-j tile: barrier; ds_write prefetched K/V; issue global prefetch of next tile; barrier;
// S^T = K@Q^T -> P=exp2(S) -> wave-private Pt -> O += P@V (no intra-compute barrier).
// Epilogue: per-row dot with W_out -> scalar partial per row (kills O-partial HBM traffic).
static constexpr int KS = 0;          // [64][136] shorts (17408 B)
static constexpr int VS = 8704;       // [128][72] shorts (18432 B)
static constexpr int PS = 17920;      // [128][72] shorts (18432 B)
__global__ __launch_bounds__(256, 2) void k_flash(const unsigned short* __restrict__ qg,
                                                  const unsigned short* __restrict__ kg,
                                                  const unsigned short* __restrict__ vtg,
                                                  const float* __restrict__ wout,
                                                  float* __restrict__ os,
                                                  float* __restrict__ lp,
                                                  int jrange) {
    __shared__ __align__(16) unsigned short lds[27136];   // 54272 B
    const int tid = threadIdx.x;
    const int i0 = blockIdx.x * 128;
    const int w = tid >> 6, lane = tid & 63;
    const int lr = lane & 15, lk = lane >> 4;

    // Q fragments (bf16, pre-scaled) in registers: rows w*32..+32
    short8 qf[2][4];
#pragma unroll
    for (int mt = 0; mt < 2; ++mt)
#pragma unroll
        for (int ks = 0; ks < 4; ++ks)
            qf[mt][ks] = *(const short8*)(qg + (size_t)(i0 + w * 32 + mt * 16 + lr) * 128 + ks * 32 + lk * 8);

    // W_out column for this lane's d-positions
    float wo[8];
#pragma unroll
    for (int dt = 0; dt < 8; ++dt) wo[dt] = wout[dt * 16 + lr];

    floatx4 oacc[2][8];
    float lsum[2] = {0.f, 0.f};
#pragma unroll
    for (int mt = 0; mt < 2; ++mt)
#pragma unroll
        for (int dt = 0; dt < 8; ++dt) oacc[mt][dt] = (floatx4)0.0f;

    const int jbase = blockIdx.y * jrange;
    const int ntile = jrange >> 6;
    const int krow = tid >> 2, kq = (tid & 3) << 5;   // K: 64 rows, 4 thr/row, 32 shorts each
    const int vrow = tid >> 1, vq = (tid & 1) << 5;   // V^T: 128 rows, 2 thr/row, 32 shorts each

    short8 pk4[4], pv4[4];
    {   // prefetch tile 0 into registers
        const unsigned short* gk = kg + (size_t)(jbase + krow) * 128 + kq;
        const unsigned short* gv = vtg + (size_t)vrow * 8192 + jbase + vq;
#pragma unroll
        for (int i = 0; i < 4; ++i) { pk4[i] = *(const short8*)(gk + i * 8); pv4[i] = *(const short8*)(gv + i * 8); }
    }

    for (int jt = 0; jt < ntile; ++jt) {
        __syncthreads();                 // previous tile's compute done; LDS free
        {   // commit prefetched tile to LDS
            unsigned short* dk = lds + KS + krow * 136 + kq;
            unsigned short* dv = lds + VS + vrow * 72 + vq;
#pragma unroll
            for (int i = 0; i < 4; ++i) { *(short8*)(dk + i * 8) = pk4[i]; *(short8*)(dv + i * 8) = pv4[i]; }
        }
        if (jt + 1 < ntile) {            // issue global prefetch of next tile (lands during compute)
            int j0 = jbase + (jt + 1) * 64;
            const unsigned short* gk = kg + (size_t)(j0 + krow) * 128 + kq;
            const unsigned short* gv = vtg + (size_t)vrow * 8192 + j0 + vq;
#pragma unroll
            for (int i = 0; i < 4; ++i) { pk4[i] = *(const short8*)(gk + i * 8); pv4[i] = *(const short8*)(gv + i * 8); }
        }
        __syncthreads();                 // staging visible

        // S^T = K @ Q^T : 64 j rows x this wave's 32 m cols
        floatx4 sacc[4][2];
#pragma unroll
        for (int j4 = 0; j4 < 4; ++j4) { sacc[j4][0] = (floatx4)0.0f; sacc[j4][1] = (floatx4)0.0f; }
#pragma unroll
        for (int ks = 0; ks < 4; ++ks) {
            short8 af[4];
#pragma unroll
            for (int j4 = 0; j4 < 4; ++j4)
                af[j4] = *(const short8*)(lds + KS + (j4 * 16 + lr) * 136 + ks * 32 + lk * 8);
#pragma unroll
            for (int j4 = 0; j4 < 4; ++j4)
#pragma unroll
                for (int mt = 0; mt < 2; ++mt)
                    sacc[j4][mt] = MFMA16(af[j4], qf[mt][ks], sacc[j4][mt]);
        }
        // P = exp2(S) -> bf16 wave-private Pt rows; accumulate l
#pragma unroll
        for (int mt = 0; mt < 2; ++mt) {
            unsigned short* prow = lds + PS + (w * 32 + mt * 16 + lr) * 72;
            float ls = 0.f;
#pragma unroll
            for (int j4 = 0; j4 < 4; ++j4) {
                float p0 = __builtin_amdgcn_exp2f(sacc[j4][mt][0]);
                float p1 = __builtin_amdgcn_exp2f(sacc[j4][mt][1]);
                float p2 = __builtin_amdgcn_exp2f(sacc[j4][mt][2]);
                float p3 = __builtin_amdgcn_exp2f(sacc[j4][mt][3]);
                ls += (p0 + p1) + (p2 + p3);
                uint2 pk;
                pk.x = packbf(p0, p1);
                pk.y = packbf(p2, p3);
                *(uint2*)(prow + j4 * 16 + lk * 4) = pk;
            }
            lsum[mt] += ls;
        }
        // O += P @ V (own Pt rows + shared Vs; wave-order DS guarantees RAW)
#pragma unroll
        for (int k2 = 0; k2 < 2; ++k2) {
            short8 pa[2], vb[8];
#pragma unroll
            for (int mt = 0; mt < 2; ++mt)
                pa[mt] = *(const short8*)(lds + PS + (w * 32 + mt * 16 + lr) * 72 + k2 * 32 + lk * 8);
#pragma unroll
            for (int dt = 0; dt < 8; ++dt)
                vb[dt] = *(const short8*)(lds + VS + (dt * 16 + lr) * 72 + k2 * 32 + lk * 8);
#pragma unroll
            for (int mt = 0; mt < 2; ++mt)
#pragma unroll
                for (int dt = 0; dt < 8; ++dt)
                    oacc[mt][dt] = MFMA16(pa[mt], vb[dt], oacc[mt][dt]);
        }
    }

    // l partials
#pragma unroll
    for (int mt = 0; mt < 2; ++mt) {
        float v = lsum[mt];
        v += __shfl_xor(v, 16);
        v += __shfl_xor(v, 32);
        if (lk == 0)
            lp[(size_t)blockIdx.y * 8192 + i0 + w * 32 + mt * 16 + lr] = v;
    }
    // O @ W_out partials: per-lane fma over d, reduce across the 16 lr lanes
#pragma unroll
    for (int mt = 0; mt < 2; ++mt) {
        floatx4 part = (floatx4)0.0f;
#pragma unroll
        for (int dt = 0; dt < 8; ++dt) part += oacc[mt][dt] * wo[dt];
#pragma unroll
        for (int d = 1; d < 16; d <<= 1) {
            floatx4 o;
            o[0] = __shfl_xor(part[0], d); o[1] = __shfl_xor(part[1], d);
            o[2] = __shfl_xor(part[2], d); o[3] = __shfl_xor(part[3], d);
            part += o;
        }
        if (lr == 0)
            *(floatx4*)(os + (size_t)blockIdx.y * 8192 + i0 + w * 32 + mt * 16 + lk * 4) = part;
    }
}

// ---------- K4: out[row] = (sum_s o_s) / (sum_s l_s) + b_out ----------
__global__ __launch_bounds__(256) void k_out(const float* __restrict__ os,
                                             const float* __restrict__ lp,
                                             const float* __restrict__ bout,
                                             float* __restrict__ out, int nsplit) {
    int row = blockIdx.x * 256 + threadIdx.x;
    float o = 0.f, l = 0.f;
    for (int s = 0; s < nsplit; ++s) {
        o += os[(size_t)s * 8192 + row];
        l += lp[(size_t)s * 8192 + row];
    }
    out[row] = o / l + bout[0];
}

// ---------- launch ----------
extern "C" void kernel_launch(void* const* d_in, const int* in_sizes, int n_in,
                              void* d_out, int out_size, void* d_ws, size_t ws_size,
                              hipStream_t stream) {
    const float* x    = (const float*)d_in[0];
    const float* Wfc  = (const float*)d_in[1];
    const float* bfc  = (const float*)d_in[2];
    const float* Wg   = (const float*)d_in[3];
    const float* bg   = (const float*)d_in[4];
    const float* Wq   = (const float*)d_in[5];
    const float* bq   = (const float*)d_in[6];
    const float* Wk   = (const float*)d_in[7];
    const float* bk   = (const float*)d_in[8];
    const float* Wv   = (const float*)d_in[9];
    const float* bv   = (const float*)d_in[10];
    const float* Wout = (const float*)d_in[11];
    const float* bout = (const float*)d_in[12];
    char* ws = (char*)d_ws;

    unsigned short* xbb  = (unsigned short*)(ws + XB_OFF);
    unsigned short* qb   = (unsigned short*)(ws + Q_OFF);
    unsigned short* kb   = (unsigned short*)(ws + K_OFF);
    unsigned short* vtb  = (unsigned short*)(ws + VT_OFF);
    unsigned short* wfct = (unsigned short*)(ws + WFCT_OFF);
    unsigned short* wgt  = (unsigned short*)(ws + WGT_OFF);
    unsigned short* wqt  = (unsigned short*)(ws + WQT_OFF);
    unsigned short* wkt  = (unsigned short*)(ws + WKT_OFF);
    unsigned short* wvt  = (unsigned short*)(ws + WVT_OFF);
    float* lpb = (float*)(ws + LP_OFF);
    float* osb = (float*)(ws + OS_OFF);

    int nsplit = 1;
    if (ws_size >= OS_OFF + 8u * 32768) nsplit = 8;
    else if (ws_size >= OS_OFF + 4u * 32768) nsplit = 4;
    else if (ws_size >= OS_OFF + 2u * 32768) nsplit = 2;

    k_xcvt<<<4096, 256, 0, stream>>>(x, xbb);
    k_transw_all<<<1216, 256, 0, stream>>>(Wfc, Wg, Wq, Wk, Wv, wfct, wgt, wqt, wkt, wvt);
    k_gq<<<256, 512, 0, stream>>>(xbb, wfct, wgt, bfc, bg, wqt, wkt, wvt, bq, bk, bv, qb, kb, vtb);

    dim3 gf(64, nsplit);
    k_flash<<<gf, 256, 0, stream>>>(qb, kb, vtb, Wout, osb, lpb, 8192 / nsplit);

    k_out<<<32, 256, 0, stream>>>(osb, lpb, bout, (float*)d_out, nsplit);
}